// Round 12
// baseline (136.724 us; speedup 1.0000x reference)
//
#include <hip/hip_runtime.h>
#include <hip/hip_bf16.h>

// Problem constants
#define M_TOK 4928   // B*T = 64*77
#define M_PAD 5120   // Xb/H2 row allocation (gemm2 reads 20x256 M-tiles)
#define D_DIM 768
#define NR    4096   // N*R = 1024*4
#define K_CAT 4864   // NR + D_DIM (concat-K for gemm2)
#define KT_ALL 152   // K_CAT / 32 (BK32 units)

typedef __bf16 bf16;
typedef __attribute__((ext_vector_type(8))) __bf16 bf16x8;
typedef __attribute__((ext_vector_type(4))) float f32x4;
typedef __attribute__((address_space(1))) uint32_t gu32;
typedef __attribute__((address_space(3))) uint32_t su32;

// ALWAYS offset=0: R11 showed a nonzero offset immediate shifts the LDS
// destination (left LDS gaps -> uninit reads -> NaN). Tile advance must be
// baked into the global pointer.
#define GLDS(P, LDSP) \
  __builtin_amdgcn_global_load_lds((gu32*)(P), (su32*)(LDSP), 16, 0, 0)

// sigma-GELU: x * sigmoid(1.702 x).  Max abs err vs exact gelu ~1e-2 on h1;
// propagated through mid_w (~0.02) the up-path contribution is <1e-3 --
// output error stays dominated by bf16 org-path rounding (1.56e-2 vs 5.8e-2).
__device__ __forceinline__ float act_fast(float v) {
  float e = __builtin_amdgcn_exp2f(v * -2.4554677f);
  return v * __builtin_amdgcn_rcpf(1.0f + e);
}

// m204 bijective XCD swizzle: consecutive logical wgids land on one XCD.
__device__ __forceinline__ int xcd_swizzle(int orig, int nwg) {
  const int q = nwg >> 3, r = nwg & 7;
  const int x = orig & 7, rest = orig >> 3;
  return (x < r ? x * (q + 1) : r * (q + 1) + (x - r) * q) + rest;
}

// ---------------- prep kernels ----------------

__global__ __launch_bounds__(256) void k_prep_x(const float* __restrict__ x,
                                                bf16* __restrict__ Xb) {
  int idx = (blockIdx.x * 256 + threadIdx.x) * 4;
  if (idx >= M_PAD * D_DIM) return;
  int m = idx / D_DIM;
  union { uint2 u; bf16 h[4]; } o;
  if (m < M_TOK) {
    float4 v = *(const float4*)(x + idx);
    o.h[0] = (bf16)v.x; o.h[1] = (bf16)v.y; o.h[2] = (bf16)v.z; o.h[3] = (bf16)v.w;
  } else {
    o.h[0] = o.h[1] = o.h[2] = o.h[3] = (bf16)0.0f;
  }
  *(uint2*)(Xb + idx) = o.u;
}

// w1 fp32 [N=1024][D=768][R=4] -> W1t bf16 [4096 j][768 d].
__global__ __launch_bounds__(256) void k_prep_w1t(const float* __restrict__ w1,
                                                  bf16* __restrict__ W1t) {
  int gid = blockIdx.x * 256 + threadIdx.x;   // 1024*96 = 98304
  int n = gid / 96, oct = gid % 96;
  const float4* src = (const float4*)w1 + (size_t)n * D_DIM + oct * 8;
  bf16x8 rows[4];
#pragma unroll
  for (int d = 0; d < 8; ++d) {
    float4 v = src[d];
    rows[0][d] = (bf16)v.x; rows[1][d] = (bf16)v.y;
    rows[2][d] = (bf16)v.z; rows[3][d] = (bf16)v.w;
  }
  size_t base = (size_t)n * 4 * D_DIM + oct * 8;
#pragma unroll
  for (int r = 0; r < 4; ++r)
    *(bf16x8*)(W1t + base + (size_t)r * D_DIM) = rows[r];
}

// w_out fp32 [4096 k][768 d] -> W2t[d][k] (x0.25) via LDS 64x64 transpose.
__global__ __launch_bounds__(256) void k_prep_w2t_t(const float* __restrict__ w_out,
                                                    bf16* __restrict__ W2t) {
  __shared__ float S[64 * 65];
  const int bk = blockIdx.x & 63, bd = blockIdx.x >> 6;
  const int k0 = bk * 64, d0 = bd * 64;
  const int tr = threadIdx.x >> 4;
  const int tc = (threadIdx.x & 15) * 4;
#pragma unroll
  for (int p = 0; p < 4; ++p) {
    const int kr = tr + p * 16;
    float4 v = *(const float4*)(w_out + (size_t)(k0 + kr) * D_DIM + d0 + tc);
    S[kr * 65 + tc + 0] = v.x; S[kr * 65 + tc + 1] = v.y;
    S[kr * 65 + tc + 2] = v.z; S[kr * 65 + tc + 3] = v.w;
  }
  __syncthreads();
#pragma unroll
  for (int p = 0; p < 4; ++p) {
    const int dr = tr + p * 16;
    union { uint2 u; bf16 h[4]; } o;
#pragma unroll
    for (int i = 0; i < 4; ++i) o.h[i] = (bf16)(0.25f * S[(tc + i) * 65 + dr]);
    *(uint2*)(W2t + (size_t)(d0 + dr) * K_CAT + k0 + tc) = o.u;
  }
}

// W_org fp32 [768 d][768 k] -> W2t[d][4096 + k]
__global__ __launch_bounds__(256) void k_prep_w2t_org(const float* __restrict__ W_org,
                                                      bf16* __restrict__ W2t) {
  int idx = (blockIdx.x * 256 + threadIdx.x) * 4;
  if (idx >= D_DIM * D_DIM) return;
  int d = idx / D_DIM, c = idx % D_DIM;
  float4 v = *(const float4*)(W_org + idx);
  union { uint2 u; bf16 h[4]; } o;
  o.h[0] = (bf16)v.x; o.h[1] = (bf16)v.y; o.h[2] = (bf16)v.z; o.h[3] = (bf16)v.w;
  *(uint2*)(W2t + (size_t)d * K_CAT + NR + c) = o.u;
}

// bias partial: sum 32 n's of b_out per block
__global__ __launch_bounds__(256) void k_bias_partial(const float* __restrict__ b_out,
                                                      float* __restrict__ partial) {
  int b = blockIdx.x;
  for (int d = threadIdx.x; d < D_DIM; d += 256) {
    float s = 0.0f;
    for (int n = b * 32; n < b * 32 + 32; ++n) s += b_out[n * D_DIM + d];
    partial[b * D_DIM + d] = s;
  }
}

// blocks 0-2: bias_total; blocks 3-18: diag[j] = mid_w[n][r][r]
__global__ __launch_bounds__(256) void k_bias_final2(const float* __restrict__ partial,
                                                     const float* __restrict__ b_org,
                                                     const float* __restrict__ mid_w,
                                                     float* __restrict__ bias_total,
                                                     float* __restrict__ diag) {
  int b = blockIdx.x;
  if (b < 3) {
    int d = b * 256 + threadIdx.x;
    if (d >= D_DIM) return;
    float s = 0.0f;
#pragma unroll
    for (int p = 0; p < 32; ++p) s += partial[p * D_DIM + d];
    bias_total[d] = b_org[d] + 0.25f * s;
  } else {
    int j = (b - 3) * 256 + threadIdx.x;
    diag[j] = mid_w[(j >> 2) * 16 + (j & 3) * 5];
  }
}

// ---------------- staging helpers ----------------
// Bank-conflict swizzle (R4-verified: conflicts -> 0): 16B slot p of row r
// holds logical slot p ^ ((r>>1)&3); source pre-swizzled, ds_read XORs back.

__device__ __forceinline__ int swz_slot(int kg, int lr) {
  return (kg ^ ((lr >> 1) & 3)) << 3;  // bf16 elements
}

// 8-wave (512-thread) stage of a 256x32 bf16 tile: 2 insts/wave (gemm2).
__device__ __forceinline__ void stage_unit8(const bf16* g, int ld, int row0, int col0,
                                            bf16* lds) {
  const int lane = threadIdx.x & 63;
  const int wave = threadIdx.x >> 6;
  const int src_slot = (lane & 3) ^ ((lane >> 3) & 3);
#pragma unroll
  for (int c = 0; c < 2; ++c) {
    const int chunk = wave * 2 + c;
    const int row = row0 + chunk * 16 + (lane >> 2);
    const bf16* gp = g + (size_t)row * ld + col0 + (src_slot << 3);
    GLDS(gp, lds + chunk * 512);
  }
}

#define TILE_E (128 * 32)

// ---------------- GEMM1: 128x128, 4 waves, 3-slot counted-vmcnt --------------
// Unrolled-by-3 pipe: compile-time LDS slots (ds_read base + offset imm, no
// runtime slot select) and persistent staging pointers bumped +32 elems per
// stage (offset imm always 0 -- see GLDS note).  Program order per iter is the
// R6-R10-verified schedule: vmcnt(4) -> barrier -> ds_read slot kt%3 ->
// stage tile kt+2 into slot (kt+2)%3 -> 16 MFMA (swapped operands).

#define G1_IT(S_, DO_STG, LAST_)                                                \
  {                                                                             \
    if (LAST_) { asm volatile("s_waitcnt vmcnt(0)" ::: "memory"); }             \
    else       { asm volatile("s_waitcnt vmcnt(4)" ::: "memory"); }             \
    asm volatile("s_barrier" ::: "memory");                                     \
    bf16x8 a_[4], b_[4];                                                        \
    _Pragma("unroll") for (int i = 0; i < 4; ++i)                               \
      a_[i] = *(const bf16x8*)(&As[S_][aOff + i * 512]);                        \
    _Pragma("unroll") for (int j = 0; j < 4; ++j)                               \
      b_[j] = *(const bf16x8*)(&Bs[S_][bOff + j * 512]);                        \
    if (DO_STG) {                                                               \
      GLDS(aP0, &As[((S_) + 2) % 3][ldsC0]);                                    \
      GLDS(aP1, &As[((S_) + 2) % 3][ldsC1]);                                    \
      GLDS(bP0, &Bs[((S_) + 2) % 3][ldsC0]);                                    \
      GLDS(bP1, &Bs[((S_) + 2) % 3][ldsC1]);                                    \
      aP0 += 32; aP1 += 32; bP0 += 32; bP1 += 32;                               \
    }                                                                           \
    _Pragma("unroll") for (int i = 0; i < 4; ++i)                               \
      _Pragma("unroll") for (int j = 0; j < 4; ++j)                             \
        acc[i][j] = __builtin_amdgcn_mfma_f32_16x16x32_bf16(b_[j], a_[i], acc[i][j], 0, 0, 0); \
  }

__global__ __launch_bounds__(256) void k_gemm1(const bf16* __restrict__ Xb,
                                               const bf16* __restrict__ W1t,
                                               bf16* __restrict__ H2,
                                               const float* __restrict__ b1,
                                               const float* __restrict__ diag,
                                               const float* __restrict__ midb) {
  __shared__ bf16 As[3][TILE_E];
  __shared__ bf16 Bs[3][TILE_E];
  const int wgid = xcd_swizzle(blockIdx.x, 39 * 32);
  const int bmt = wgid >> 5;             // 39 M-tiles of 128
  const int bnt = wgid & 31;             // 32 N-tiles (consecutive share A-panel)
  const int m0 = bmt * 128, n0 = bnt * 128;
  const int lane = threadIdx.x & 63;
  const int wave = threadIdx.x >> 6;
  const int wm = wave >> 1, wn = wave & 1;
  const int lr = lane & 15, kg = lane >> 4;
  const int slot = swz_slot(kg, lr);
  const int aOff = (wm * 64 + lr) * 32 + slot;
  const int bOff = (wn * 64 + lr) * 32 + slot;

  // persistent staging pointers (2 chunks each for A and B), bumped per stage
  const int src_slot = (lane & 3) ^ ((lane >> 3) & 3);
  const int srow = (wave * 2) * 16 + (lane >> 2);
  const bf16* aP0 = Xb  + (size_t)(m0 + srow) * D_DIM + (src_slot << 3);
  const bf16* aP1 = aP0 + 16 * D_DIM;
  const bf16* bP0 = W1t + (size_t)(n0 + srow) * D_DIM + (src_slot << 3);
  const bf16* bP1 = bP0 + 16 * D_DIM;
  const int ldsC0 = (wave * 2) * 512, ldsC1 = ldsC0 + 512;

  f32x4 acc[4][4];
#pragma unroll
  for (int i = 0; i < 4; ++i)
#pragma unroll
    for (int j = 0; j < 4; ++j) acc[i][j] = (f32x4)(0.0f);

  // prologue: tile 0 -> slot 0, tile 1 -> slot 1 (pointer bump between)
  GLDS(aP0, &As[0][ldsC0]); GLDS(aP1, &As[0][ldsC1]);
  GLDS(bP0, &Bs[0][ldsC0]); GLDS(bP1, &Bs[0][ldsC1]);
  aP0 += 32; aP1 += 32; bP0 += 32; bP1 += 32;
  GLDS(aP0, &As[1][ldsC0]); GLDS(aP1, &As[1][ldsC1]);
  GLDS(bP0, &Bs[1][ldsC0]); GLDS(bP1, &Bs[1][ldsC1]);
  aP0 += 32; aP1 += 32; bP0 += 32; bP1 += 32;   // now at tile 2

  for (int g = 0; g < 7; ++g) {                 // kt = 0..20, stage tiles 2..22
    G1_IT(0, true, false)
    G1_IT(1, true, false)
    G1_IT(2, true, false)
  }
  G1_IT(0, true, false)                         // kt=21 (stages tile 23)
  G1_IT(1, false, false)                        // kt=22
  G1_IT(2, false, true)                         // kt=23

  // epilogue: lane owns H2[mr][jcb..jcb+3] per frag (swapped-MFMA layout)
#pragma unroll
  for (int j = 0; j < 4; ++j) {
    const int jcb = n0 + wn * 64 + j * 16 + kg * 4;
    const float4 b1v = *(const float4*)(b1 + jcb);
    const float4 dgv = *(const float4*)(diag + jcb);
    const float4 mbv = *(const float4*)(midb + jcb);
#pragma unroll
    for (int i = 0; i < 4; ++i) {
      const int mr = m0 + wm * 64 + i * 16 + lr;
      union { uint2 u; bf16 h[4]; } o;
      float h;
      h = act_fast(acc[i][j][0] + b1v.x); o.h[0] = (bf16)act_fast(h * dgv.x + mbv.x);
      h = act_fast(acc[i][j][1] + b1v.y); o.h[1] = (bf16)act_fast(h * dgv.y + mbv.y);
      h = act_fast(acc[i][j][2] + b1v.z); o.h[2] = (bf16)act_fast(h * dgv.z + mbv.z);
      h = act_fast(acc[i][j][3] + b1v.w); o.h[3] = (bf16)act_fast(h * dgv.w + mbv.w);
      *(uint2*)(H2 + (size_t)mr * NR + jcb) = o.u;
    }
  }
}

// ---------------- GEMM2: 256x256 8-wave engine (R8/R10, unchanged) ----------

#define ENGINE(KT0, KT1, STAGE_A, STAGE_B)                                      \
  {                                                                             \
    STAGE_A((KT0) + 0, 0); STAGE_B((KT0) + 0, 0);                               \
    STAGE_A((KT0) + 1, 1); STAGE_B((KT0) + 1, 1);                               \
    STAGE_A((KT0) + 2, 2); STAGE_B((KT0) + 2, 2);                               \
    asm volatile("s_waitcnt vmcnt(8)" ::: "memory");                            \
    asm volatile("s_barrier" ::: "memory");                                     \
    for (int t = (KT0); t < (KT1); ++t) {                                       \
      const int s  = (t - (KT0)) & 3;                                           \
      const int st = (t - (KT0) + 3) & 3;                                       \
      const bool more = (t + 3 < (KT1));                                        \
      bf16x8 a[8], b[4];                                                        \
      _Pragma("unroll") for (int i = 0; i < 4; ++i)                             \
        a[i] = *(const bf16x8*)(As[s] + aBase + i * 512);                       \
      _Pragma("unroll") for (int j = 0; j < 4; ++j)                             \
        b[j] = *(const bf16x8*)(Bs[s] + bBase + j * 512);                       \
      if (more) { STAGE_A(t + 3, st); }                                         \
      asm volatile("s_barrier" ::: "memory");                                   \
      __builtin_amdgcn_s_setprio(1);                                            \
      _Pragma("unroll") for (int i = 0; i < 4; ++i)                             \
        _Pragma("unroll") for (int j = 0; j < 4; ++j)                           \
          acc[i][j] = __builtin_amdgcn_mfma_f32_16x16x32_bf16(b[j], a[i], acc[i][j], 0, 0, 0); \
      __builtin_amdgcn_s_setprio(0);                                            \
      asm volatile("s_barrier" ::: "memory");                                   \
      _Pragma("unroll") for (int i = 0; i < 4; ++i)                             \
        a[4 + i] = *(const bf16x8*)(As[s] + aBase + 2048 + i * 512);            \
      if (more) { STAGE_B(t + 3, st); }                                         \
      {                                                                         \
        int ahead = ((KT1) - 1) - (t + 1);                                      \
        if (ahead >= 2)      { asm volatile("s_waitcnt vmcnt(8)" ::: "memory"); } \
        else if (ahead == 1) { asm volatile("s_waitcnt vmcnt(4)" ::: "memory"); } \
        else                 { asm volatile("s_waitcnt vmcnt(0)" ::: "memory"); } \
      }                                                                         \
      asm volatile("s_barrier" ::: "memory");                                   \
      __builtin_amdgcn_s_setprio(1);                                            \
      _Pragma("unroll") for (int i = 0; i < 4; ++i)                             \
        _Pragma("unroll") for (int j = 0; j < 4; ++j)                           \
          acc[4 + i][j] = __builtin_amdgcn_mfma_f32_16x16x32_bf16(b[j], a[4 + i], acc[4 + i][j], 0, 0, 0); \
      __builtin_amdgcn_s_setprio(0);                                            \
      asm volatile("s_barrier" ::: "memory");                                   \
    }                                                                           \
  }

template <int SPLITS>
__global__ __launch_bounds__(512) void k_gemm2(const bf16* __restrict__ H2,
                                               const bf16* __restrict__ Xb,
                                               const bf16* __restrict__ W2t,
                                               void* __restrict__ outp,
                                               const float* __restrict__ bias) {
  __shared__ bf16 As[4][8192];
  __shared__ bf16 Bs[4][8192];
  const int nwg = 20 * 3 * SPLITS;
  const int wgid = xcd_swizzle(blockIdx.x, nwg);
  const int bmt = wgid / (3 * SPLITS);
  const int rem = wgid % (3 * SPLITS);
  const int ks  = rem / 3;
  const int bnt = rem % 3;
  const int m0 = bmt * 256, n0 = bnt * 256;
  const int lane = threadIdx.x & 63;
  const int wave = threadIdx.x >> 6;
  const int wm = wave >> 2, wn = wave & 3;
  const int lr = lane & 15, kg = lane >> 4;
  const int slotE = swz_slot(kg, lr);
  const int aBase = (wm * 128 + lr) * 32 + slotE;
  const int bBase = (wn * 64 + lr) * 32 + slotE;
  constexpr int KT_PER = KT_ALL / SPLITS;
  const int kt0 = ks * KT_PER, kt1 = kt0 + KT_PER;

  f32x4 acc[8][4];
#pragma unroll
  for (int i = 0; i < 8; ++i)
#pragma unroll
    for (int j = 0; j < 4; ++j) acc[i][j] = (f32x4)(0.0f);

#define G2_SA(kt, buf)                                                  \
  {                                                                     \
    const int k0s = (kt) * 32;                                          \
    if (k0s < NR) stage_unit8(H2, NR, m0, k0s, As[(buf)]);              \
    else          stage_unit8(Xb, D_DIM, m0, k0s - NR, As[(buf)]);      \
  }
#define G2_SB(kt, buf) stage_unit8(W2t, K_CAT, n0, (kt) * 32, Bs[(buf)])
  ENGINE(kt0, kt1, G2_SA, G2_SB)
#undef G2_SA
#undef G2_SB

  if (SPLITS > 1) {
    bf16* dst = (bf16*)outp + (size_t)ks * M_TOK * D_DIM;
#pragma unroll
    for (int j = 0; j < 4; ++j) {
      const int cb = n0 + wn * 64 + j * 16 + kg * 4;
#pragma unroll
      for (int i = 0; i < 8; ++i) {
        const int mr = m0 + wm * 128 + i * 16 + lr;
        if (mr < M_TOK) {
          union { uint2 u; bf16 h[4]; } o;
          o.h[0] = (bf16)acc[i][j][0]; o.h[1] = (bf16)acc[i][j][1];
          o.h[2] = (bf16)acc[i][j][2]; o.h[3] = (bf16)acc[i][j][3];
          *(uint2*)(dst + (size_t)mr * D_DIM + cb) = o.u;
        }
      }
    }
  } else {
    float* dst = (float*)outp;
#pragma unroll
    for (int j = 0; j < 4; ++j) {
      const int cb = n0 + wn * 64 + j * 16 + kg * 4;
      const f32x4 bv = *(const f32x4*)(bias + cb);
#pragma unroll
      for (int i = 0; i < 8; ++i) {
        const int mr = m0 + wm * 128 + i * 16 + lr;
        if (mr < M_TOK) {
          f32x4 o = acc[i][j] + bv;
          *(f32x4*)(dst + (size_t)mr * D_DIM + cb) = o;
        }
      }
    }
  }
}

// out = sum_s bf16 partial[s] + bias
template <int SPLITS>
__global__ __launch_bounds__(256) void k_reduce(const bf16* __restrict__ padd,
                                                const float* __restrict__ bias,
                                                float* __restrict__ out) {
  int idx = (blockIdx.x * 256 + threadIdx.x) * 4;
  if (idx >= M_TOK * D_DIM) return;
  float4 s = *(const float4*)(bias + (idx % D_DIM));
#pragma unroll
  for (int p = 0; p < SPLITS; ++p) {
    union { uint2 u; bf16 h[4]; } v;
    v.u = *(const uint2*)(padd + (size_t)p * M_TOK * D_DIM + idx);
    s.x += (float)v.h[0]; s.y += (float)v.h[1];
    s.z += (float)v.h[2]; s.w += (float)v.h[3];
  }
  *(float4*)(out + idx) = s;
}

// ---------------- launch ----------------

extern "C" void kernel_launch(void* const* d_in, const int* in_sizes, int n_in,
                              void* d_out, int out_size, void* d_ws, size_t ws_size,
                              hipStream_t stream) {
  const float* x     = (const float*)d_in[0];
  const float* W_org = (const float*)d_in[1];
  const float* b_org = (const float*)d_in[2];
  const float* w1    = (const float*)d_in[3];
  const float* b1    = (const float*)d_in[4];
  const float* mid_w = (const float*)d_in[5];
  const float* mid_b = (const float*)d_in[6];
  const float* w_out = (const float*)d_in[7];
  const float* b_out = (const float*)d_in[8];
  float* out = (float*)d_out;

  // workspace carve-up
  bf16* Xb   = (bf16*)d_ws;                         // 5120*768
  bf16* W1t  = Xb  + (size_t)M_PAD * D_DIM;         // 4096*768
  bf16* W2t  = W1t + (size_t)NR * D_DIM;            // 768*4864
  bf16* H2   = W2t + (size_t)D_DIM * K_CAT;         // 5120*4096
  float* bias    = (float*)(H2 + (size_t)M_PAD * NR);
  float* partial = bias + 1024;                     // 32*768 floats
  float* diag    = partial + 32 * D_DIM;            // 4096 floats
  bf16* padd     = (bf16*)(diag + NR);              // SPLITS * 4928*768 bf16

  const size_t base_bytes = (size_t)((char*)padd - (char*)d_ws);
  const size_t per_split  = (size_t)M_TOK * D_DIM * sizeof(bf16);
  int S = 1;
  if (ws_size >= base_bytes + 4 * per_split)      S = 4;
  else if (ws_size >= base_bytes + 2 * per_split) S = 2;

  k_prep_x     <<<(M_PAD * D_DIM / 4) / 256, 256, 0, stream>>>(x, Xb);
  k_prep_w1t   <<<384, 256, 0, stream>>>(w1, W1t);
  k_prep_w2t_t <<<64 * 12, 256, 0, stream>>>(w_out, W2t);
  k_prep_w2t_org<<<(D_DIM * D_DIM / 4 + 255) / 256, 256, 0, stream>>>(W_org, W2t);
  k_bias_partial<<<32, 256, 0, stream>>>(b_out, partial);
  k_bias_final2 <<<19, 256, 0, stream>>>(partial, b_org, mid_w, bias, diag);

  k_gemm1<<<39 * 32, 256, 0, stream>>>(Xb, W1t, H2, b1, diag, mid_b);

  const int red_grid = (M_TOK * D_DIM / 4 + 255) / 256;
  if (S == 4) {
    k_gemm2<4><<<20 * 3 * 4, 512, 0, stream>>>(H2, Xb, W2t, padd, bias);
    k_reduce<4><<<red_grid, 256, 0, stream>>>(padd, bias, out);
  } else if (S == 2) {
    k_gemm2<2><<<20 * 3 * 2, 512, 0, stream>>>(H2, Xb, W2t, padd, bias);
    k_reduce<2><<<red_grid, 256, 0, stream>>>(padd, bias, out);
  } else {
    k_gemm2<1><<<20 * 3, 512, 0, stream>>>(H2, Xb, W2t, out, bias);
  }
}

// Round 13
// 118.893 us; speedup vs baseline: 1.1500x; 1.1500x over previous
//
#include <hip/hip_runtime.h>
#include <hip/hip_bf16.h>

// Problem constants
#define M_TOK 4928   // B*T = 64*77
#define M_PAD 5120   // Xb/H2 row allocation (gemm2 reads 20x256 M-tiles)
#define D_DIM 768
#define NR    4096   // N*R = 1024*4
#define K_CAT 4864   // NR + D_DIM (concat-K for gemm2)
#define KT_ALL 152   // K_CAT / 32 (BK32 units)

typedef __bf16 bf16;
typedef unsigned char u8;   // raw fp8 e4m3 byte
typedef __attribute__((ext_vector_type(8))) __bf16 bf16x8;
typedef __attribute__((ext_vector_type(4))) float f32x4;
typedef __attribute__((address_space(1))) uint32_t gu32;
typedef __attribute__((address_space(3))) uint32_t su32;

// ALWAYS offset=0: R11 showed a nonzero offset immediate shifts the LDS
// destination (left LDS gaps -> uninit reads -> NaN). Tile advance must be
// baked into the global pointer.
#define GLDS(P, LDSP) \
  __builtin_amdgcn_global_load_lds((gu32*)(P), (su32*)(LDSP), 16, 0, 0)

// pack 4 f32 -> 4 fp8 e4m3 (RNE, saturating) in one u32
__device__ __forceinline__ uint32_t pk_fp8x4(float a, float b, float c, float d) {
  uint32_t w = 0;
  w = (uint32_t)__builtin_amdgcn_cvt_pk_fp8_f32(a, b, (int)w, false);
  w = (uint32_t)__builtin_amdgcn_cvt_pk_fp8_f32(c, d, (int)w, true);
  return w;
}

// sigma-GELU: x * sigmoid(1.702 x).  Max abs err vs exact gelu ~1e-2 on h1;
// propagated through mid_w (~0.02) the up-path contribution is <1e-3 --
// output error stays dominated by bf16 org-path rounding (1.56e-2 vs 5.8e-2).
__device__ __forceinline__ float act_fast(float v) {
  float e = __builtin_amdgcn_exp2f(v * -2.4554677f);
  return v * __builtin_amdgcn_rcpf(1.0f + e);
}

// m204 bijective XCD swizzle: consecutive logical wgids land on one XCD.
__device__ __forceinline__ int xcd_swizzle(int orig, int nwg) {
  const int q = nwg >> 3, r = nwg & 7;
  const int x = orig & 7, rest = orig >> 3;
  return (x < r ? x * (q + 1) : r * (q + 1) + (x - r) * q) + rest;
}

// ---------------- prep kernels ----------------

__global__ __launch_bounds__(256) void k_prep_x(const float* __restrict__ x,
                                                bf16* __restrict__ Xb) {
  int idx = (blockIdx.x * 256 + threadIdx.x) * 4;
  if (idx >= M_PAD * D_DIM) return;
  int m = idx / D_DIM;
  union { uint2 u; bf16 h[4]; } o;
  if (m < M_TOK) {
    float4 v = *(const float4*)(x + idx);
    o.h[0] = (bf16)v.x; o.h[1] = (bf16)v.y; o.h[2] = (bf16)v.z; o.h[3] = (bf16)v.w;
  } else {
    o.h[0] = o.h[1] = o.h[2] = o.h[3] = (bf16)0.0f;
  }
  *(uint2*)(Xb + idx) = o.u;
}

// x fp32 -> Xq fp8 e4m3 [5120x768], pad rows zero.  X ~ N(0,1): no scale.
__global__ __launch_bounds__(256) void k_prep_xq(const float* __restrict__ x,
                                                 u8* __restrict__ Xq) {
  int idx = (blockIdx.x * 256 + threadIdx.x) * 4;
  if (idx >= M_PAD * D_DIM) return;
  int m = idx / D_DIM;
  uint32_t w = 0;
  if (m < M_TOK) {
    float4 v = *(const float4*)(x + idx);
    w = pk_fp8x4(v.x, v.y, v.z, v.w);
  }
  *(uint32_t*)(Xq + idx) = w;
}

// w1 fp32 [N=1024][D=768][R=4] -> W1q fp8 [4096 j][768 d], scaled x64
// (w1 std 0.02 sits in e4m3 denormal range; x64 -> std 1.28; epilogue /64).
__global__ __launch_bounds__(256) void k_prep_w1q(const float* __restrict__ w1,
                                                  u8* __restrict__ W1q) {
  int gid = blockIdx.x * 256 + threadIdx.x;   // 1024*96 = 98304
  int n = gid / 96, oct = gid % 96;
  const float4* src = (const float4*)w1 + (size_t)n * D_DIM + oct * 8;
  float e[4][8];
#pragma unroll
  for (int d = 0; d < 8; ++d) {
    float4 v = src[d];
    e[0][d] = v.x * 64.0f; e[1][d] = v.y * 64.0f;
    e[2][d] = v.z * 64.0f; e[3][d] = v.w * 64.0f;
  }
  size_t base = (size_t)n * 4 * D_DIM + oct * 8;
#pragma unroll
  for (int r = 0; r < 4; ++r) {
    uint2 o;
    o.x = pk_fp8x4(e[r][0], e[r][1], e[r][2], e[r][3]);
    o.y = pk_fp8x4(e[r][4], e[r][5], e[r][6], e[r][7]);
    *(uint2*)(W1q + base + (size_t)r * D_DIM) = o;
  }
}

// w_out fp32 [4096 k][768 d] -> W2t[d][k] (x0.25) via LDS 64x64 transpose.
__global__ __launch_bounds__(256) void k_prep_w2t_t(const float* __restrict__ w_out,
                                                    bf16* __restrict__ W2t) {
  __shared__ float S[64 * 65];
  const int bk = blockIdx.x & 63, bd = blockIdx.x >> 6;
  const int k0 = bk * 64, d0 = bd * 64;
  const int tr = threadIdx.x >> 4;
  const int tc = (threadIdx.x & 15) * 4;
#pragma unroll
  for (int p = 0; p < 4; ++p) {
    const int kr = tr + p * 16;
    float4 v = *(const float4*)(w_out + (size_t)(k0 + kr) * D_DIM + d0 + tc);
    S[kr * 65 + tc + 0] = v.x; S[kr * 65 + tc + 1] = v.y;
    S[kr * 65 + tc + 2] = v.z; S[kr * 65 + tc + 3] = v.w;
  }
  __syncthreads();
#pragma unroll
  for (int p = 0; p < 4; ++p) {
    const int dr = tr + p * 16;
    union { uint2 u; bf16 h[4]; } o;
#pragma unroll
    for (int i = 0; i < 4; ++i) o.h[i] = (bf16)(0.25f * S[(tc + i) * 65 + dr]);
    *(uint2*)(W2t + (size_t)(d0 + dr) * K_CAT + k0 + tc) = o.u;
  }
}

// W_org fp32 [768 d][768 k] -> W2t[d][4096 + k]
__global__ __launch_bounds__(256) void k_prep_w2t_org(const float* __restrict__ W_org,
                                                      bf16* __restrict__ W2t) {
  int idx = (blockIdx.x * 256 + threadIdx.x) * 4;
  if (idx >= D_DIM * D_DIM) return;
  int d = idx / D_DIM, c = idx % D_DIM;
  float4 v = *(const float4*)(W_org + idx);
  union { uint2 u; bf16 h[4]; } o;
  o.h[0] = (bf16)v.x; o.h[1] = (bf16)v.y; o.h[2] = (bf16)v.z; o.h[3] = (bf16)v.w;
  *(uint2*)(W2t + (size_t)d * K_CAT + NR + c) = o.u;
}

// bias partial: sum 32 n's of b_out per block
__global__ __launch_bounds__(256) void k_bias_partial(const float* __restrict__ b_out,
                                                      float* __restrict__ partial) {
  int b = blockIdx.x;
  for (int d = threadIdx.x; d < D_DIM; d += 256) {
    float s = 0.0f;
    for (int n = b * 32; n < b * 32 + 32; ++n) s += b_out[n * D_DIM + d];
    partial[b * D_DIM + d] = s;
  }
}

// blocks 0-2: bias_total; blocks 3-18: diag[j] = mid_w[n][r][r]
__global__ __launch_bounds__(256) void k_bias_final2(const float* __restrict__ partial,
                                                     const float* __restrict__ b_org,
                                                     const float* __restrict__ mid_w,
                                                     float* __restrict__ bias_total,
                                                     float* __restrict__ diag) {
  int b = blockIdx.x;
  if (b < 3) {
    int d = b * 256 + threadIdx.x;
    if (d >= D_DIM) return;
    float s = 0.0f;
#pragma unroll
    for (int p = 0; p < 32; ++p) s += partial[p * D_DIM + d];
    bias_total[d] = b_org[d] + 0.25f * s;
  } else {
    int j = (b - 3) * 256 + threadIdx.x;
    diag[j] = mid_w[(j >> 2) * 16 + (j & 3) * 5];
  }
}

// ---------------- staging helpers ----------------
// Bank-conflict swizzle (R4-verified: conflicts -> 0): 16B slot p of row r
// holds logical slot p ^ ((r>>1)&3); source pre-swizzled, ds_read XORs back.

__device__ __forceinline__ int swz_slot(int kg, int lr) {
  return (kg ^ ((lr >> 1) & 3)) << 3;  // bf16 elements
}

// 8-wave (512-thread) stage of a 256x32 bf16 tile: 2 insts/wave (gemm2).
__device__ __forceinline__ void stage_unit8(const bf16* g, int ld, int row0, int col0,
                                            bf16* lds) {
  const int lane = threadIdx.x & 63;
  const int wave = threadIdx.x >> 6;
  const int src_slot = (lane & 3) ^ ((lane >> 3) & 3);
#pragma unroll
  for (int c = 0; c < 2; ++c) {
    const int chunk = wave * 2 + c;
    const int row = row0 + chunk * 16 + (lane >> 2);
    const bf16* gp = g + (size_t)row * ld + col0 + (src_slot << 3);
    GLDS(gp, lds + chunk * 512);
  }
}

// ---------------- GEMM1: fp8, 128x128 tile, BK=64, 3-slot counted-vmcnt -----
// Tile = 128 rows x 64 K of fp8 = 8 KB (64B rows, 4 x 16B slots) -- SAME
// geometry as the bf16/BK32 version, so the verified swizzle/stage carry over.
// 12 iters x 32 fp8-MFMA; per iter 16 x ds_read_b64 (half the bytes of R12).
// k-slice 1 of each frag = byte offset ^ 32 (slot bit1; rows are 64B-clean).

#define G1F_IT(S_, DO_STG, LAST_)                                               \
  {                                                                             \
    if (LAST_) { asm volatile("s_waitcnt vmcnt(0)" ::: "memory"); }             \
    else       { asm volatile("s_waitcnt vmcnt(4)" ::: "memory"); }             \
    asm volatile("s_barrier" ::: "memory");                                     \
    long a0[4], a1[4], b0[4], b1[4];                                            \
    _Pragma("unroll") for (int i = 0; i < 4; ++i) {                             \
      a0[i] = *(const long*)(&As[S_][aOff + i * 1024]);                         \
      a1[i] = *(const long*)(&As[S_][(aOff ^ 32) + i * 1024]);                  \
    }                                                                           \
    _Pragma("unroll") for (int j = 0; j < 4; ++j) {                             \
      b0[j] = *(const long*)(&Bs[S_][bOff + j * 1024]);                         \
      b1[j] = *(const long*)(&Bs[S_][(bOff ^ 32) + j * 1024]);                  \
    }                                                                           \
    if (DO_STG) {                                                               \
      GLDS(aP0, &As[((S_) + 2) % 3][ldsC0]);                                    \
      GLDS(aP1, &As[((S_) + 2) % 3][ldsC1]);                                    \
      GLDS(bP0, &Bs[((S_) + 2) % 3][ldsC0]);                                    \
      GLDS(bP1, &Bs[((S_) + 2) % 3][ldsC1]);                                    \
      aP0 += 64; aP1 += 64; bP0 += 64; bP1 += 64;                               \
    }                                                                           \
    _Pragma("unroll") for (int i = 0; i < 4; ++i)                               \
      _Pragma("unroll") for (int j = 0; j < 4; ++j)                             \
        acc[i][j] = __builtin_amdgcn_mfma_f32_16x16x32_fp8_fp8(b0[j], a0[i], acc[i][j], 0, 0, 0); \
    _Pragma("unroll") for (int i = 0; i < 4; ++i)                               \
      _Pragma("unroll") for (int j = 0; j < 4; ++j)                             \
        acc[i][j] = __builtin_amdgcn_mfma_f32_16x16x32_fp8_fp8(b1[j], a1[i], acc[i][j], 0, 0, 0); \
  }

__global__ __launch_bounds__(256) void k_gemm1(const u8* __restrict__ Xq,
                                               const u8* __restrict__ W1q,
                                               bf16* __restrict__ H2,
                                               const float* __restrict__ b1,
                                               const float* __restrict__ diag,
                                               const float* __restrict__ midb) {
  __shared__ u8 As[3][128 * 64];
  __shared__ u8 Bs[3][128 * 64];
  const int wgid = xcd_swizzle(blockIdx.x, 39 * 32);
  const int bmt = wgid >> 5;             // 39 M-tiles of 128
  const int bnt = wgid & 31;             // 32 N-tiles (consecutive share A-panel)
  const int m0 = bmt * 128, n0 = bnt * 128;
  const int lane = threadIdx.x & 63;
  const int wave = threadIdx.x >> 6;
  const int wm = wave >> 1, wn = wave & 1;
  const int lr = lane & 15, kg = lane >> 4;
  // k-slice 0 byte offset in a 64B row: slot (kg>>1) ^ swz, sub (kg&1)*8
  const int slotB = (((kg >> 1) ^ ((lr >> 1) & 3)) << 4) + ((kg & 1) << 3);
  const int aOff = (wm * 64 + lr) * 64 + slotB;
  const int bOff = (wn * 64 + lr) * 64 + slotB;

  // persistent staging pointers (2 chunks each for A and B), bumped per stage
  const int src_slot = (lane & 3) ^ ((lane >> 3) & 3);
  const int srow = (wave * 2) * 16 + (lane >> 2);
  const u8* aP0 = Xq  + (size_t)(m0 + srow) * D_DIM + (src_slot << 4);
  const u8* aP1 = aP0 + 16 * D_DIM;
  const u8* bP0 = W1q + (size_t)(n0 + srow) * D_DIM + (src_slot << 4);
  const u8* bP1 = bP0 + 16 * D_DIM;
  const int ldsC0 = (wave * 2) * 1024, ldsC1 = ldsC0 + 1024;

  f32x4 acc[4][4];
#pragma unroll
  for (int i = 0; i < 4; ++i)
#pragma unroll
    for (int j = 0; j < 4; ++j) acc[i][j] = (f32x4)(0.0f);

  // prologue: tile 0 -> slot 0, tile 1 -> slot 1
  GLDS(aP0, &As[0][ldsC0]); GLDS(aP1, &As[0][ldsC1]);
  GLDS(bP0, &Bs[0][ldsC0]); GLDS(bP1, &Bs[0][ldsC1]);
  aP0 += 64; aP1 += 64; bP0 += 64; bP1 += 64;
  GLDS(aP0, &As[1][ldsC0]); GLDS(aP1, &As[1][ldsC1]);
  GLDS(bP0, &Bs[1][ldsC0]); GLDS(bP1, &Bs[1][ldsC1]);
  aP0 += 64; aP1 += 64; bP0 += 64; bP1 += 64;   // now at tile 2

  for (int g = 0; g < 3; ++g) {                 // iters 0..8, stage tiles 2..10
    G1F_IT(0, true, false)
    G1F_IT(1, true, false)
    G1F_IT(2, true, false)
  }
  G1F_IT(0, true, false)                        // iter 9 (stages tile 11)
  G1F_IT(1, false, false)                       // iter 10
  G1F_IT(2, false, true)                        // iter 11

  // epilogue: lane owns H2[mr][jcb..jcb+3] per frag (swapped-MFMA layout).
  // acc = 64*h1 (W1q scale) -> x 2^-6 exactly.
#pragma unroll
  for (int j = 0; j < 4; ++j) {
    const int jcb = n0 + wn * 64 + j * 16 + kg * 4;
    const float4 b1v = *(const float4*)(b1 + jcb);
    const float4 dgv = *(const float4*)(diag + jcb);
    const float4 mbv = *(const float4*)(midb + jcb);
#pragma unroll
    for (int i = 0; i < 4; ++i) {
      const int mr = m0 + wm * 64 + i * 16 + lr;
      union { uint2 u; bf16 h[4]; } o;
      float h;
      h = act_fast(fmaf(acc[i][j][0], 0.015625f, b1v.x)); o.h[0] = (bf16)act_fast(h * dgv.x + mbv.x);
      h = act_fast(fmaf(acc[i][j][1], 0.015625f, b1v.y)); o.h[1] = (bf16)act_fast(h * dgv.y + mbv.y);
      h = act_fast(fmaf(acc[i][j][2], 0.015625f, b1v.z)); o.h[2] = (bf16)act_fast(h * dgv.z + mbv.z);
      h = act_fast(fmaf(acc[i][j][3], 0.015625f, b1v.w)); o.h[3] = (bf16)act_fast(h * dgv.w + mbv.w);
      *(uint2*)(H2 + (size_t)mr * NR + jcb) = o.u;
    }
  }
}

// ---------------- GEMM2: 256x256 8-wave engine (R8/R10/R12, unchanged) ------

#define ENGINE(KT0, KT1, STAGE_A, STAGE_B)                                      \
  {                                                                             \
    STAGE_A((KT0) + 0, 0); STAGE_B((KT0) + 0, 0);                               \
    STAGE_A((KT0) + 1, 1); STAGE_B((KT0) + 1, 1);                               \
    STAGE_A((KT0) + 2, 2); STAGE_B((KT0) + 2, 2);                               \
    asm volatile("s_waitcnt vmcnt(8)" ::: "memory");                            \
    asm volatile("s_barrier" ::: "memory");                                     \
    for (int t = (KT0); t < (KT1); ++t) {                                       \
      const int s  = (t - (KT0)) & 3;                                           \
      const int st = (t - (KT0) + 3) & 3;                                       \
      const bool more = (t + 3 < (KT1));                                        \
      bf16x8 a[8], b[4];                                                        \
      _Pragma("unroll") for (int i = 0; i < 4; ++i)                             \
        a[i] = *(const bf16x8*)(As[s] + aBase + i * 512);                       \
      _Pragma("unroll") for (int j = 0; j < 4; ++j)                             \
        b[j] = *(const bf16x8*)(Bs[s] + bBase + j * 512);                       \
      if (more) { STAGE_A(t + 3, st); }                                         \
      asm volatile("s_barrier" ::: "memory");                                   \
      __builtin_amdgcn_s_setprio(1);                                            \
      _Pragma("unroll") for (int i = 0; i < 4; ++i)                             \
        _Pragma("unroll") for (int j = 0; j < 4; ++j)                           \
          acc[i][j] = __builtin_amdgcn_mfma_f32_16x16x32_bf16(b[j], a[i], acc[i][j], 0, 0, 0); \
      __builtin_amdgcn_s_setprio(0);                                            \
      asm volatile("s_barrier" ::: "memory");                                   \
      _Pragma("unroll") for (int i = 0; i < 4; ++i)                             \
        a[4 + i] = *(const bf16x8*)(As[s] + aBase + 2048 + i * 512);            \
      if (more) { STAGE_B(t + 3, st); }                                         \
      {                                                                         \
        int ahead = ((KT1) - 1) - (t + 1);                                      \
        if (ahead >= 2)      { asm volatile("s_waitcnt vmcnt(8)" ::: "memory"); } \
        else if (ahead == 1) { asm volatile("s_waitcnt vmcnt(4)" ::: "memory"); } \
        else                 { asm volatile("s_waitcnt vmcnt(0)" ::: "memory"); } \
      }                                                                         \
      asm volatile("s_barrier" ::: "memory");                                   \
      __builtin_amdgcn_s_setprio(1);                                            \
      _Pragma("unroll") for (int i = 0; i < 4; ++i)                             \
        _Pragma("unroll") for (int j = 0; j < 4; ++j)                           \
          acc[4 + i][j] = __builtin_amdgcn_mfma_f32_16x16x32_bf16(b[j], a[4 + i], acc[4 + i][j], 0, 0, 0); \
      __builtin_amdgcn_s_setprio(0);                                            \
      asm volatile("s_barrier" ::: "memory");                                   \
    }                                                                           \
  }

template <int SPLITS>
__global__ __launch_bounds__(512) void k_gemm2(const bf16* __restrict__ H2,
                                               const bf16* __restrict__ Xb,
                                               const bf16* __restrict__ W2t,
                                               void* __restrict__ outp,
                                               const float* __restrict__ bias) {
  __shared__ bf16 As[4][8192];
  __shared__ bf16 Bs[4][8192];
  const int nwg = 20 * 3 * SPLITS;
  const int wgid = xcd_swizzle(blockIdx.x, nwg);
  const int bmt = wgid / (3 * SPLITS);
  const int rem = wgid % (3 * SPLITS);
  const int ks  = rem / 3;
  const int bnt = rem % 3;
  const int m0 = bmt * 256, n0 = bnt * 256;
  const int lane = threadIdx.x & 63;
  const int wave = threadIdx.x >> 6;
  const int wm = wave >> 2, wn = wave & 3;
  const int lr = lane & 15, kg = lane >> 4;
  const int slotE = swz_slot(kg, lr);
  const int aBase = (wm * 128 + lr) * 32 + slotE;
  const int bBase = (wn * 64 + lr) * 32 + slotE;
  constexpr int KT_PER = KT_ALL / SPLITS;
  const int kt0 = ks * KT_PER, kt1 = kt0 + KT_PER;

  f32x4 acc[8][4];
#pragma unroll
  for (int i = 0; i < 8; ++i)
#pragma unroll
    for (int j = 0; j < 4; ++j) acc[i][j] = (f32x4)(0.0f);

#define G2_SA(kt, buf)                                                  \
  {                                                                     \
    const int k0s = (kt) * 32;                                          \
    if (k0s < NR) stage_unit8(H2, NR, m0, k0s, As[(buf)]);              \
    else          stage_unit8(Xb, D_DIM, m0, k0s - NR, As[(buf)]);      \
  }
#define G2_SB(kt, buf) stage_unit8(W2t, K_CAT, n0, (kt) * 32, Bs[(buf)])
  ENGINE(kt0, kt1, G2_SA, G2_SB)
#undef G2_SA
#undef G2_SB

  if (SPLITS > 1) {
    bf16* dst = (bf16*)outp + (size_t)ks * M_TOK * D_DIM;
#pragma unroll
    for (int j = 0; j < 4; ++j) {
      const int cb = n0 + wn * 64 + j * 16 + kg * 4;
#pragma unroll
      for (int i = 0; i < 8; ++i) {
        const int mr = m0 + wm * 128 + i * 16 + lr;
        if (mr < M_TOK) {
          union { uint2 u; bf16 h[4]; } o;
          o.h[0] = (bf16)acc[i][j][0]; o.h[1] = (bf16)acc[i][j][1];
          o.h[2] = (bf16)acc[i][j][2]; o.h[3] = (bf16)acc[i][j][3];
          *(uint2*)(dst + (size_t)mr * D_DIM + cb) = o.u;
        }
      }
    }
  } else {
    float* dst = (float*)outp;
#pragma unroll
    for (int j = 0; j < 4; ++j) {
      const int cb = n0 + wn * 64 + j * 16 + kg * 4;
      const f32x4 bv = *(const f32x4*)(bias + cb);
#pragma unroll
      for (int i = 0; i < 8; ++i) {
        const int mr = m0 + wm * 128 + i * 16 + lr;
        if (mr < M_TOK) {
          f32x4 o = acc[i][j] + bv;
          *(f32x4*)(dst + (size_t)mr * D_DIM + cb) = o;
        }
      }
    }
  }
}

// out = sum_s bf16 partial[s] + bias
template <int SPLITS>
__global__ __launch_bounds__(256) void k_reduce(const bf16* __restrict__ padd,
                                                const float* __restrict__ bias,
                                                float* __restrict__ out) {
  int idx = (blockIdx.x * 256 + threadIdx.x) * 4;
  if (idx >= M_TOK * D_DIM) return;
  float4 s = *(const float4*)(bias + (idx % D_DIM));
#pragma unroll
  for (int p = 0; p < SPLITS; ++p) {
    union { uint2 u; bf16 h[4]; } v;
    v.u = *(const uint2*)(padd + (size_t)p * M_TOK * D_DIM + idx);
    s.x += (float)v.h[0]; s.y += (float)v.h[1];
    s.z += (float)v.h[2]; s.w += (float)v.h[3];
  }
  *(float4*)(out + idx) = s;
}

// ---------------- launch ----------------

extern "C" void kernel_launch(void* const* d_in, const int* in_sizes, int n_in,
                              void* d_out, int out_size, void* d_ws, size_t ws_size,
                              hipStream_t stream) {
  const float* x     = (const float*)d_in[0];
  const float* W_org = (const float*)d_in[1];
  const float* b_org = (const float*)d_in[2];
  const float* w1    = (const float*)d_in[3];
  const float* b1    = (const float*)d_in[4];
  const float* mid_w = (const float*)d_in[5];
  const float* mid_b = (const float*)d_in[6];
  const float* w_out = (const float*)d_in[7];
  const float* b_out = (const float*)d_in[8];
  float* out = (float*)d_out;

  // workspace carve-up
  bf16* Xb   = (bf16*)d_ws;                         // 5120*768
  bf16* W2t  = Xb  + (size_t)M_PAD * D_DIM;         // 768*4864
  bf16* H2   = W2t + (size_t)D_DIM * K_CAT;         // 5120*4096
  float* bias    = (float*)(H2 + (size_t)M_PAD * NR);
  float* partial = bias + 1024;                     // 32*768 floats
  float* diag    = partial + 32 * D_DIM;            // 4096 floats
  u8*   Xq   = (u8*)(diag + NR);                    // 5120*768 fp8
  u8*   W1q  = Xq + (size_t)M_PAD * D_DIM;          // 4096*768 fp8
  bf16* padd = (bf16*)(W1q + (size_t)NR * D_DIM);   // SPLITS * 4928*768 bf16

  const size_t base_bytes = (size_t)((char*)padd - (char*)d_ws);
  const size_t per_split  = (size_t)M_TOK * D_DIM * sizeof(bf16);
  int S = 1;
  if (ws_size >= base_bytes + 4 * per_split)      S = 4;
  else if (ws_size >= base_bytes + 2 * per_split) S = 2;

  k_prep_x      <<<(M_PAD * D_DIM / 4) / 256, 256, 0, stream>>>(x, Xb);
  k_prep_xq     <<<(M_PAD * D_DIM / 4) / 256, 256, 0, stream>>>(x, Xq);
  k_prep_w1q    <<<384, 256, 0, stream>>>(w1, W1q);
  k_prep_w2t_t  <<<64 * 12, 256, 0, stream>>>(w_out, W2t);
  k_prep_w2t_org<<<(D_DIM * D_DIM / 4 + 255) / 256, 256, 0, stream>>>(W_org, W2t);
  k_bias_partial<<<32, 256, 0, stream>>>(b_out, partial);
  k_bias_final2 <<<19, 256, 0, stream>>>(partial, b_org, mid_w, bias, diag);

  k_gemm1<<<39 * 32, 256, 0, stream>>>(Xq, W1q, H2, b1, diag, mid_b);

  const int red_grid = (M_TOK * D_DIM / 4 + 255) / 256;
  if (S == 4) {
    k_gemm2<4><<<20 * 3 * 4, 512, 0, stream>>>(H2, Xb, W2t, padd, bias);
    k_reduce<4><<<red_grid, 256, 0, stream>>>(padd, bias, out);
  } else if (S == 2) {
    k_gemm2<2><<<20 * 3 * 2, 512, 0, stream>>>(H2, Xb, W2t, padd, bias);
    k_reduce<2><<<red_grid, 256, 0, stream>>>(padd, bias, out);
  } else {
    k_gemm2<1><<<20 * 3, 512, 0, stream>>>(H2, Xb, W2t, out, bias);
  }
}